// Round 13
// baseline (178.274 us; speedup 1.0000x reference)
//
#include <hip/hip_runtime.h>
#include <hip/hip_bf16.h>

typedef __hip_bfloat16 bf16;
typedef __attribute__((ext_vector_type(8))) short short8;
typedef __attribute__((ext_vector_type(4))) short s4;
typedef __attribute__((ext_vector_type(4))) float f32x4;

// Problem dims (hard-coded per reference)
constexpr int Bd = 2, Ld = 2048, DM = 512, Ed = 1024, Nn = 16, Rr = 32, Kc = 4;
constexpr int Md = Bd * Ld;  // 4096 rows
constexpr int CS = 32, NC = Ld / CS;  // chunked scan: 64 chunks of 32

__device__ __forceinline__ float b2f(bf16 v) { return __bfloat162float(v); }
__device__ __forceinline__ float s2f(short s) {
  return __uint_as_float(((unsigned int)(unsigned short)s) << 16);
}

__device__ __forceinline__ void gld_lds16(const void* g, void* l) {
  __builtin_amdgcn_global_load_lds(
      (const __attribute__((address_space(1))) unsigned int*)g,
      (__attribute__((address_space(3))) unsigned int*)l, 16, 0, 0);
}

// ---------------- 0+1. merged weight casts (float4-vectorized) + RMSNorm ----------------
// blocks [0, 1632): cast 4 elements/thread of in_proj|out_proj|x_proj|dt_proj
//   (boundaries in float4 units: 262144 / 393216 / 409600 / 417792)
// blocks [1632, 1632+4096): RMSNorm row (block - 1632)
__global__ __launch_bounds__(256) void castnorm_k(const float* __restrict__ ip,
                                                  const float* __restrict__ op,
                                                  const float* __restrict__ xp,
                                                  const float* __restrict__ dt,
                                                  bf16* __restrict__ ipb,
                                                  bf16* __restrict__ opb,
                                                  bf16* __restrict__ xpb,
                                                  bf16* __restrict__ dtb,
                                                  const float* __restrict__ x,
                                                  const float* __restrict__ w,
                                                  bf16* __restrict__ xn) {
  int bid = blockIdx.x;
  if (bid < 1632) {
    int i4 = bid * 256 + threadIdx.x;
    const float* src;
    bf16* dst;
    if (i4 < 262144) {
      src = ip; dst = ipb;
    } else if (i4 < 393216) {
      i4 -= 262144; src = op; dst = opb;
    } else if (i4 < 409600) {
      i4 -= 393216; src = xp; dst = xpb;
    } else {
      i4 -= 409600; src = dt; dst = dtb;
    }
    float4 v = *(const float4*)(src + (size_t)i4 * 4);
    s4 o;
    bf16 b0 = __float2bfloat16(v.x); o[0] = *(short*)&b0;
    bf16 b1 = __float2bfloat16(v.y); o[1] = *(short*)&b1;
    bf16 b2 = __float2bfloat16(v.z); o[2] = *(short*)&b2;
    bf16 b3 = __float2bfloat16(v.w); o[3] = *(short*)&b3;
    *(s4*)(dst + (size_t)i4 * 4) = o;
    return;
  }
  int row = bid - 1632;
  const float* xr = x + (size_t)row * DM;
  float ss = 0.f;
  for (int i = threadIdx.x; i < DM; i += 256) {
    float v = xr[i];
    ss += v * v;
  }
  for (int o = 32; o > 0; o >>= 1) ss += __shfl_down(ss, o, 64);
  __shared__ float smem[4];
  int wid = threadIdx.x >> 6, lid = threadIdx.x & 63;
  if (lid == 0) smem[wid] = ss;
  __syncthreads();
  if (threadIdx.x == 0) {
    float t = smem[0] + smem[1] + smem[2] + smem[3];
    smem[0] = rsqrtf(t / (float)DM + 1e-5f);
  }
  __syncthreads();
  float sc = smem[0];
  for (int i = threadIdx.x; i < DM; i += 256) {
    xn[(size_t)row * DM + i] = __float2bfloat16(xr[i] * sc * w[i]);
  }
}

// ---------------- bf16 MFMA GEMM: C[M,N] = A[M,K] * W[N,K]^T ----------------
// BM/BN template, BK=64, 256 threads (4 waves, 2x2 wave grid; wave tile BM/2 x BN/2).
// MODE 0: bf16 to Cb. MODE 1: f32 (acc + R) to Cf.
// Smaller tiles -> lower VGPR/LDS -> more blocks/CU for cross-block latency overlap
// (confirmed win on out_proj r12; now applied to in_proj as 128x64).
template <int MODE, int BM, int BN>
__global__ __launch_bounds__(256) void gemm_mfma(const bf16* __restrict__ A,
                                                 const bf16* __restrict__ W,
                                                 bf16* __restrict__ Cb,
                                                 float* __restrict__ Cf,
                                                 const float* __restrict__ R,
                                                 int Kd, int Nd) {
  __shared__ __align__(16) short lsA[BM * 64];
  __shared__ __align__(16) short lsB[BN * 64];
  constexpr int TM = BM / 32;
  constexpr int TN = BN / 32;
  int tid = threadIdx.x, lane = tid & 63, wid = tid >> 6;
  int wm = wid >> 1, wn = wid & 1;
  int m0 = blockIdx.y * BM, n0 = blockIdx.x * BN;
  int lrow = lane >> 3, lq = lane & 7;
  int mloc = lane & 15, quad = lane >> 4, mx = mloc & 7;
  f32x4 acc[TM][TN] = {};

  for (int k0 = 0; k0 < Kd; k0 += 64) {
    __syncthreads();
    #pragma unroll
    for (int i = 0; i < BM / 32; ++i) {
      int r0 = wid * (BM / 4) + i * 8;
      int r = r0 + lrow;
      int qg = lq ^ (r & 7);
      gld_lds16(A + (size_t)(m0 + r) * Kd + k0 + qg * 8, &lsA[r0 * 64]);
    }
    #pragma unroll
    for (int i = 0; i < BN / 32; ++i) {
      int r0 = wid * (BN / 4) + i * 8;
      int r = r0 + lrow;
      int qg = lq ^ (r & 7);
      gld_lds16(W + (size_t)(n0 + r) * Kd + k0 + qg * 8, &lsB[r0 * 64]);
    }
    __syncthreads();
    #pragma unroll
    for (int kk = 0; kk < 2; ++kk) {
      short8 aF[TM], bF[TN];
      int cc = (kk << 2) + quad;
      int cp = (cc ^ mx) << 3;
      #pragma unroll
      for (int t = 0; t < TM; ++t)
        aF[t] = *(const short8*)&lsA[(wm * (BM / 2) + t * 16 + mloc) * 64 + cp];
      #pragma unroll
      for (int t = 0; t < TN; ++t)
        bF[t] = *(const short8*)&lsB[(wn * (BN / 2) + t * 16 + mloc) * 64 + cp];
      #pragma unroll
      for (int tm = 0; tm < TM; ++tm)
        #pragma unroll
        for (int tn = 0; tn < TN; ++tn)
          acc[tm][tn] = __builtin_amdgcn_mfma_f32_16x16x32_bf16(
              aF[tm], bF[tn], acc[tm][tn], 0, 0, 0);
    }
  }

  #pragma unroll
  for (int tm = 0; tm < TM; ++tm) {
    #pragma unroll
    for (int reg = 0; reg < 4; ++reg) {
      int row = m0 + wm * (BM / 2) + tm * 16 + quad * 4 + reg;
      #pragma unroll
      for (int tn = 0; tn < TN; ++tn) {
        int col = n0 + wn * (BN / 2) + tn * 16 + mloc;
        float v = acc[tm][tn][reg];
        if (MODE == 0) {
          Cb[(size_t)row * Nd + col] = __float2bfloat16(v);
        } else {
          Cf[(size_t)row * Nd + col] = v + R[(size_t)row * Nd + col];
        }
      }
    }
  }
}

// ---------------- 3+4. fused conv+SiLU -> x_proj MFMA (16-row tiles, r9-proven) ------
__global__ __launch_bounds__(256, 1) void cpk_k(const bf16* __restrict__ xzb,
                                                const float* __restrict__ cw,
                                                const float* __restrict__ cb,
                                                const bf16* __restrict__ xpb,
                                                bf16* __restrict__ xsb,
                                                bf16* __restrict__ dltb,
                                                float* __restrict__ dbc) {
  __shared__ __align__(16) short lsXZ[19 * 1024];  // staged xz x-half rows [m0-3, m0+16)
  __shared__ __align__(16) short lsX[16 * 1024];   // xs tile, chunk-XOR swizzled
  int t = threadIdx.x, lane = t & 63, wv = t >> 6;
  int ml = lane & 15, quad = lane >> 4;
  int m0 = blockIdx.x * 16;
  int bs = m0 & ~(Ld - 1);  // batch start row

  // x_proj weight prefetch: wave wv -> output cols wv*16..wv*16+15
  short8 bF[32];
  #pragma unroll
  for (int ks = 0; ks < 32; ++ks)
    bF[ks] = *(const short8*)(xpb + (size_t)(wv * 16 + ml) * Ed + ks * 32 + quad * 8);

  // phase A: stage xz x-half rows
  #pragma unroll
  for (int p = 0; p < 10; ++p) {
    int idx8 = t + p * 256;
    if (idx8 < 19 * 128) {
      int le = idx8 * 8;
      int r = le >> 10, e = le & 1023;
      int g = m0 - 3 + r;
      short8 v = {0, 0, 0, 0, 0, 0, 0, 0};
      if (g >= bs) v = *(const short8*)(xzb + (size_t)g * (2 * Ed) + e);
      *(short8*)&lsXZ[r * 1024 + e] = v;
    }
  }
  __syncthreads();

  // phase B: conv(K=4)+bias+SiLU on 4 consecutive e; write global + swizzled LDS
  {
    int e0 = t * 4;
    int c8 = e0 >> 3, off = e0 & 7;
    float4 cwv[4];
    #pragma unroll
    for (int j = 0; j < 4; ++j) cwv[j] = *(const float4*)(cw + (e0 + j) * 4);
    float4 cbv = *(const float4*)(cb + e0);
    float w0[4], w1[4], w2[4];
    s4 r0v = *(const s4*)&lsXZ[0 * 1024 + e0];
    s4 r1v = *(const s4*)&lsXZ[1 * 1024 + e0];
    s4 r2v = *(const s4*)&lsXZ[2 * 1024 + e0];
    #pragma unroll
    for (int j = 0; j < 4; ++j) {
      w0[j] = s2f(r0v[j]); w1[j] = s2f(r1v[j]); w2[j] = s2f(r2v[j]);
    }
    #pragma unroll
    for (int r = 0; r < 16; ++r) {
      s4 r3v = *(const s4*)&lsXZ[(r + 3) * 1024 + e0];
      s4 outv;
      #pragma unroll
      for (int j = 0; j < 4; ++j) {
        float w3 = s2f(r3v[j]);
        float a = cbv[j] + cwv[j].x * w0[j] + cwv[j].y * w1[j] +
                  cwv[j].z * w2[j] + cwv[j].w * w3;
        float s = a / (1.f + __expf(-a));
        bf16 v = __float2bfloat16(s);
        outv[j] = *(short*)&v;
        w0[j] = w1[j]; w1[j] = w2[j]; w2[j] = w3;
      }
      *(s4*)(xsb + (size_t)(m0 + r) * Ed + e0) = outv;
      *(s4*)&lsX[r * 1024 + (((c8 ^ (r & 7)) << 3)) + off] = outv;
    }
  }
  __syncthreads();

  // phase C: x_proj MFMA (weights in regs)
  f32x4 acc = {0.f, 0.f, 0.f, 0.f};
  #pragma unroll
  for (int ks = 0; ks < 32; ++ks) {
    short8 aF = *(const short8*)&lsX[ml * 1024 + (((ks * 4 + quad) ^ (ml & 7)) << 3)];
    acc = __builtin_amdgcn_mfma_f32_16x16x32_bf16(aF, bF[ks], acc, 0, 0, 0);
  }
  if (wv < 2) {
    #pragma unroll
    for (int reg = 0; reg < 4; ++reg)
      dltb[(size_t)(m0 + quad * 4 + reg) * Rr + wv * 16 + ml] =
          __float2bfloat16(acc[reg]);
  } else {
    #pragma unroll
    for (int reg = 0; reg < 4; ++reg)
      dbc[(size_t)(m0 + quad * 4 + reg) * 64 + wv * 16 + ml] = acc[reg];
  }
}

// ---------------- 5-6. dt_proj + softplus -> bf16 delta (grid 1024) ----------------
__global__ __launch_bounds__(256) void pk2_k(const bf16* __restrict__ dltb,
                                             const bf16* __restrict__ dtb,
                                             const float* __restrict__ dt_b,
                                             bf16* __restrict__ delta) {
  int t = threadIdx.x, lane = t & 63, wv = t >> 6;
  int ml = lane & 15, quad = lane >> 4;
  int rt = blockIdx.x & 255, cq = blockIdx.x >> 8;
  int m0 = rt * 16;
  int cb0 = cq * 256 + wv * 64;    // this wave: 4 col-groups of 16

  short8 aF = *(const short8*)(dltb + (size_t)(m0 + ml) * Rr + quad * 8);
  short8 bF[4];
  float bias[4];
  #pragma unroll
  for (int g = 0; g < 4; ++g) {
    int e = cb0 + g * 16 + ml;
    bF[g] = *(const short8*)(dtb + (size_t)e * Rr + quad * 8);
    bias[g] = dt_b[e];
  }
  #pragma unroll
  for (int g = 0; g < 4; ++g) {
    f32x4 dacc = {0.f, 0.f, 0.f, 0.f};
    dacc = __builtin_amdgcn_mfma_f32_16x16x32_bf16(aF, bF[g], dacc, 0, 0, 0);
    int e = cb0 + g * 16 + ml;
    #pragma unroll
    for (int reg = 0; reg < 4; ++reg) {
      float v = dacc[reg] + bias[g];
      v = (v > 20.f) ? v : log1pf(__expf(v));
      delta[(size_t)(m0 + quad * 4 + reg) * Ed + e] = __float2bfloat16(v);
    }
  }
}

// ---------------- 7a. chunk-local scan: one thread per (b,e,chunk) ----------------
__global__ __launch_bounds__(256) void scan1_k(const bf16* __restrict__ delta,
                                               const bf16* __restrict__ xs,
                                               const float* __restrict__ dbc,
                                               const float* __restrict__ Aw,
                                               float* __restrict__ Sbuf,
                                               float* __restrict__ Hbuf) {
  int bc = blockIdx.x & 127;         // b*NC + c
  int eblk = blockIdx.x >> 7;
  int e = eblk * 256 + threadIdx.x;
  int b = bc >> 6, c = bc & 63;
  float A0 = Aw[e * Nn];
  float h[16];
  #pragma unroll
  for (int n = 0; n < 16; ++n) h[n] = 0.f;
  float s = 0.f;
  size_t m0 = (size_t)b * Ld + (size_t)c * CS;
  const bf16* dp = delta + m0 * Ed + e;
  const bf16* xp = xs + m0 * Ed + e;
  const float4* bp = (const float4*)(dbc + m0 * 64 + 32);
  for (int l = 0; l < CS; l += 2) {
    float dv0 = b2f(dp[0]), dv1 = b2f(dp[Ed]);
    float xv0 = b2f(xp[0]), xv1 = b2f(xp[Ed]);
    float4 Bq0[4], Bq1[4];
    #pragma unroll
    for (int q = 0; q < 4; ++q) { Bq0[q] = bp[q]; Bq1[q] = bp[16 + q]; }
    const float* B0 = (const float*)Bq0;
    const float* B1 = (const float*)Bq1;
    {
      float r = __expf(dv0 * A0), dvx = dv0 * xv0, p = r;
      #pragma unroll
      for (int n = 0; n < 16; ++n) { h[n] = fmaf(p, h[n], B0[n] * dvx); p *= r; }
    }
    {
      float r = __expf(dv1 * A0), dvx = dv1 * xv1, p = r;
      #pragma unroll
      for (int n = 0; n < 16; ++n) { h[n] = fmaf(p, h[n], B1[n] * dvx); p *= r; }
    }
    s += dv0 + dv1;
    dp += 2 * Ed; xp += 2 * Ed; bp += 32;
  }
  size_t ch = (size_t)bc * Ed + e;
  Sbuf[ch] = s;
  float4* Hp = (float4*)(Hbuf + ch * 16);
  #pragma unroll
  for (int q = 0; q < 4; ++q) Hp[q] = ((float4*)h)[q];
}

// ---------------- 7b. chunk-prefix fix-up ----------------
__global__ __launch_bounds__(256) void scan2_k(const float* __restrict__ Sbuf,
                                               const float* __restrict__ Aw,
                                               float* __restrict__ Hbuf) {
  int idx = blockIdx.x * 256 + threadIdx.x;
  int n = idx & 15;
  int be = idx >> 4;
  int e = be & (Ed - 1);
  int b = be >> 10;
  float An = Aw[e * Nn + n];
  float h = 0.f;
  for (int c0 = 0; c0 < NC; c0 += 8) {
    float sv[8], hv[8];
    size_t ix[8];
    #pragma unroll
    for (int j = 0; j < 8; ++j) {
      size_t ch = (size_t)(b * NC + c0 + j) * Ed + e;
      ix[j] = ch * 16 + n;
      sv[j] = Sbuf[ch];
      hv[j] = Hbuf[ix[j]];
    }
    #pragma unroll
    for (int j = 0; j < 8; ++j) {
      Hbuf[ix[j]] = h;
      h = __expf(sv[j] * An) * h + hv[j];
    }
  }
}

// ---------------- 7c. re-scan from h_enter + y = C.h + D*xs, SiLU(z) gate ------------
__global__ __launch_bounds__(256) void scan3_k(const bf16* __restrict__ delta,
                                               const bf16* __restrict__ xs,
                                               const float* __restrict__ dbc,
                                               const bf16* __restrict__ xz,
                                               const float* __restrict__ Aw,
                                               const float* __restrict__ Dw,
                                               const float* __restrict__ Hbuf,
                                               bf16* __restrict__ yg) {
  int bc = blockIdx.x & 127;
  int eblk = blockIdx.x >> 7;
  int e = eblk * 256 + threadIdx.x;
  int b = bc >> 6, c = bc & 63;
  float A0 = Aw[e * Nn];
  float De = Dw[e];
  size_t ch = (size_t)bc * Ed + e;
  float h[16];
  #pragma unroll
  for (int q = 0; q < 4; ++q)
    ((float4*)h)[q] = ((const float4*)(Hbuf + ch * 16))[q];
  size_t m0 = (size_t)b * Ld + (size_t)c * CS;
  const bf16* dp = delta + m0 * Ed + e;
  const bf16* xp = xs + m0 * Ed + e;
  const float4* bp = (const float4*)(dbc + m0 * 64 + 32);  // [B(16)|C(16)]
  const bf16* zp = xz + m0 * (2 * Ed) + Ed + e;
  bf16* yp = yg + m0 * Ed + e;
  for (int l = 0; l < CS; l += 2) {
    float dv0 = b2f(dp[0]), dv1 = b2f(dp[Ed]);
    float xv0 = b2f(xp[0]), xv1 = b2f(xp[Ed]);
    float zv0 = b2f(zp[0]), zv1 = b2f(zp[2 * Ed]);
    float4 Q0[8], Q1[8];
    #pragma unroll
    for (int q = 0; q < 8; ++q) { Q0[q] = bp[q]; Q1[q] = bp[16 + q]; }
    const float* B0 = (const float*)Q0;        // B = [0..16), C = [16..32)
    const float* B1 = (const float*)Q1;
    {
      float r = __expf(dv0 * A0), dvx = dv0 * xv0, p = r;
      float y0 = 0.f, y1 = 0.f, y2 = 0.f, y3 = 0.f;
      #pragma unroll
      for (int n = 0; n < 16; ++n) {
        h[n] = fmaf(p, h[n], B0[n] * dvx);
        if ((n & 3) == 0) y0 = fmaf(h[n], B0[16 + n], y0);
        else if ((n & 3) == 1) y1 = fmaf(h[n], B0[16 + n], y1);
        else if ((n & 3) == 2) y2 = fmaf(h[n], B0[16 + n], y2);
        else y3 = fmaf(h[n], B0[16 + n], y3);
        p *= r;
      }
      float y = (y0 + y1) + (y2 + y3);
      float ytot = fmaf(De, xv0, y);
      float g = zv0 / (1.f + __expf(-zv0));
      yp[0] = __float2bfloat16(ytot * g);
    }
    {
      float r = __expf(dv1 * A0), dvx = dv1 * xv1, p = r;
      float y0 = 0.f, y1 = 0.f, y2 = 0.f, y3 = 0.f;
      #pragma unroll
      for (int n = 0; n < 16; ++n) {
        h[n] = fmaf(p, h[n], B1[n] * dvx);
        if ((n & 3) == 0) y0 = fmaf(h[n], B1[16 + n], y0);
        else if ((n & 3) == 1) y1 = fmaf(h[n], B1[16 + n], y1);
        else if ((n & 3) == 2) y2 = fmaf(h[n], B1[16 + n], y2);
        else y3 = fmaf(h[n], B1[16 + n], y3);
        p *= r;
      }
      float y = (y0 + y1) + (y2 + y3);
      float ytot = fmaf(De, xv1, y);
      float g = zv1 / (1.f + __expf(-zv1));
      yp[Ed] = __float2bfloat16(ytot * g);
    }
    dp += 2 * Ed; xp += 2 * Ed; bp += 32; zp += 4 * Ed; yp += 2 * Ed;
  }
}

extern "C" void kernel_launch(void* const* d_in, const int* in_sizes, int n_in,
                              void* d_out, int out_size, void* d_ws, size_t ws_size,
                              hipStream_t stream) {
  const float* x        = (const float*)d_in[0];
  const float* norm_w   = (const float*)d_in[1];
  const float* in_proj  = (const float*)d_in[2];
  const float* conv_w   = (const float*)d_in[3];
  const float* conv_b   = (const float*)d_in[4];
  const float* x_proj   = (const float*)d_in[5];
  const float* dt_proj  = (const float*)d_in[6];
  const float* dt_b     = (const float*)d_in[7];
  const float* Aw       = (const float*)d_in[8];
  const float* Dw       = (const float*)d_in[9];
  const float* out_proj = (const float*)d_in[10];
  float* out = (float*)d_out;

  // workspace layout (~57 MB, < 76.5 MB proven)
  char* w = (char*)d_ws;
  bf16*  xzb   = (bf16*)w;   w += (size_t)Md * 2 * Ed * 2;        // 16 MB
  bf16*  xsb   = (bf16*)w;   w += (size_t)Md * Ed * 2;            //  8 MB
  float* dbc   = (float*)w;  w += (size_t)Md * 64 * 4;            //  1 MB
  bf16*  delta = (bf16*)w;   w += (size_t)Md * Ed * 2;            //  8 MB
  bf16*  ygb   = (bf16*)w;   w += (size_t)Md * Ed * 2;            //  8 MB
  bf16*  xnb   = (bf16*)w;   w += (size_t)Md * DM * 2;            //  4 MB
  bf16*  ipb   = (bf16*)w;   w += (size_t)2 * Ed * DM * 2;        //  2 MB
  bf16*  opb   = (bf16*)w;   w += (size_t)DM * Ed * 2;            //  1 MB
  bf16*  xpb   = (bf16*)w;   w += (size_t)64 * Ed * 2;            // 128 KB
  bf16*  dtb   = (bf16*)w;   w += (size_t)Ed * Rr * 2;            //  64 KB
  bf16*  dltb  = (bf16*)w;   w += (size_t)Md * Rr * 2;            // 256 KB
  float* Sbuf  = (float*)w;  w += (size_t)Bd * Ed * NC * 4;       // 512 KB
  float* Hbuf  = (float*)w;                                       //  8 MB

  // 0+1. merged weight casts (float4-vectorized, 1632 blocks) + RMSNorm
  castnorm_k<<<1632 + Md, 256, 0, stream>>>(in_proj, out_proj, x_proj, dt_proj,
                                            ipb, opb, xpb, dtb, x, norm_w, xnb);
  // 2. xz = xn @ in_proj^T  [4096 x 2048], K=512 (MFMA 128x64, 1024 blocks = 4/CU)
  gemm_mfma<0, 128, 64><<<dim3(2 * Ed / 64, Md / 128), 256, 0, stream>>>(
      xnb, ipb, xzb, nullptr, nullptr, DM, 2 * Ed);
  // 3+4. fused conv+silu -> x_proj (16-row tiles, grid 256 -- r9-proven best)
  cpk_k<<<Md / 16, 256, 0, stream>>>(xzb, conv_w, conv_b, xpb, xsb, dltb, dbc);
  // 5-6. dt_proj + softplus -> bf16 delta (grid 1024)
  pk2_k<<<(Md / 16) * 4, 256, 0, stream>>>(dltb, dtb, dt_b, delta);
  // 7. chunked scan (thread-per-channel)
  scan1_k<<<(Bd * Ed * NC) / 256, 256, 0, stream>>>(delta, xsb, dbc, Aw, Sbuf, Hbuf);
  scan2_k<<<(Bd * Ed * Nn) / 256, 256, 0, stream>>>(Sbuf, Aw, Hbuf);
  scan3_k<<<(Bd * Ed * NC) / 256, 256, 0, stream>>>(delta, xsb, dbc, xzb, Aw, Dw, Hbuf, ygb);
  // 8. out = yg @ out_proj^T + x  [4096 x 512], K=1024 (MFMA 64x64, 512 blocks ~2/CU)
  gemm_mfma<1, 64, 64><<<dim3(DM / 64, Md / 64), 256, 0, stream>>>(
      ygb, opb, nullptr, out, x, Ed, DM);
}

// Round 14
// 175.479 us; speedup vs baseline: 1.0159x; 1.0159x over previous
//
#include <hip/hip_runtime.h>
#include <hip/hip_bf16.h>

typedef __hip_bfloat16 bf16;
typedef __attribute__((ext_vector_type(8))) short short8;
typedef __attribute__((ext_vector_type(4))) short s4;
typedef __attribute__((ext_vector_type(4))) float f32x4;

// Problem dims (hard-coded per reference)
constexpr int Bd = 2, Ld = 2048, DM = 512, Ed = 1024, Nn = 16, Rr = 32, Kc = 4;
constexpr int Md = Bd * Ld;  // 4096 rows
constexpr int CS = 32, NC = Ld / CS;  // chunked scan: 64 chunks of 32

__device__ __forceinline__ float b2f(bf16 v) { return __bfloat162float(v); }
__device__ __forceinline__ float s2f(short s) {
  return __uint_as_float(((unsigned int)(unsigned short)s) << 16);
}
__device__ __forceinline__ unsigned short f2s(float f) {
  bf16 b = __float2bfloat16(f);
  return *(unsigned short*)&b;
}

__device__ __forceinline__ void gld_lds16(const void* g, void* l) {
  __builtin_amdgcn_global_load_lds(
      (const __attribute__((address_space(1))) unsigned int*)g,
      (__attribute__((address_space(3))) unsigned int*)l, 16, 0, 0);
}

// ---------------- 0+1. merged: weight casts (f4-vec) + dbc zero + RMSNorm ----------------
// blocks [0,1632): cast 4 elem/thread of in_proj|out_proj|x_proj|dt_proj
// blocks [1632,1888): zero dbc (atomicAdd target; 256 blocks x 1024 floats)
// blocks [1888,1888+4096): RMSNorm row (block-1888)
__global__ __launch_bounds__(256) void castnorm_k(const float* __restrict__ ip,
                                                  const float* __restrict__ op,
                                                  const float* __restrict__ xp,
                                                  const float* __restrict__ dt,
                                                  bf16* __restrict__ ipb,
                                                  bf16* __restrict__ opb,
                                                  bf16* __restrict__ xpb,
                                                  bf16* __restrict__ dtb,
                                                  float* __restrict__ dbc,
                                                  const float* __restrict__ x,
                                                  const float* __restrict__ w,
                                                  bf16* __restrict__ xn) {
  int bid = blockIdx.x;
  if (bid < 1632) {
    int i4 = bid * 256 + threadIdx.x;
    const float* src;
    bf16* dst;
    if (i4 < 262144) {
      src = ip; dst = ipb;
    } else if (i4 < 393216) {
      i4 -= 262144; src = op; dst = opb;
    } else if (i4 < 409600) {
      i4 -= 393216; src = xp; dst = xpb;
    } else {
      i4 -= 409600; src = dt; dst = dtb;
    }
    float4 v = *(const float4*)(src + (size_t)i4 * 4);
    s4 o;
    o[0] = (short)f2s(v.x); o[1] = (short)f2s(v.y);
    o[2] = (short)f2s(v.z); o[3] = (short)f2s(v.w);
    *(s4*)(dst + (size_t)i4 * 4) = o;
    return;
  }
  if (bid < 1888) {
    int i4 = (bid - 1632) * 256 + threadIdx.x;  // 0..65535 float4s = 262144 floats
    float4 z = {0.f, 0.f, 0.f, 0.f};
    *(float4*)(dbc + (size_t)i4 * 4) = z;
    return;
  }
  int row = bid - 1888;
  const float* xr = x + (size_t)row * DM;
  float ss = 0.f;
  for (int i = threadIdx.x; i < DM; i += 256) {
    float v = xr[i];
    ss += v * v;
  }
  for (int o = 32; o > 0; o >>= 1) ss += __shfl_down(ss, o, 64);
  __shared__ float smem[4];
  int wid = threadIdx.x >> 6, lid = threadIdx.x & 63;
  if (lid == 0) smem[wid] = ss;
  __syncthreads();
  if (threadIdx.x == 0) {
    float t = smem[0] + smem[1] + smem[2] + smem[3];
    smem[0] = rsqrtf(t / (float)DM + 1e-5f);
  }
  __syncthreads();
  float sc = smem[0];
  for (int i = threadIdx.x; i < DM; i += 256) {
    xn[(size_t)row * DM + i] = __float2bfloat16(xr[i] * sc * w[i]);
  }
}

// ---------------- bf16 MFMA GEMM: C[M,N] = A[M,K] * W[N,K]^T ----------------
// BM/BN template, BK=64, 256 threads. MODE 0: bf16 to Cb. MODE 1: f32 (acc+R) to Cf.
template <int MODE, int BM, int BN>
__global__ __launch_bounds__(256) void gemm_mfma(const bf16* __restrict__ A,
                                                 const bf16* __restrict__ W,
                                                 bf16* __restrict__ Cb,
                                                 float* __restrict__ Cf,
                                                 const float* __restrict__ R,
                                                 int Kd, int Nd) {
  __shared__ __align__(16) short lsA[BM * 64];
  __shared__ __align__(16) short lsB[BN * 64];
  constexpr int TM = BM / 32;
  constexpr int TN = BN / 32;
  int tid = threadIdx.x, lane = tid & 63, wid = tid >> 6;
  int wm = wid >> 1, wn = wid & 1;
  int m0 = blockIdx.y * BM, n0 = blockIdx.x * BN;
  int lrow = lane >> 3, lq = lane & 7;
  int mloc = lane & 15, quad = lane >> 4, mx = mloc & 7;
  f32x4 acc[TM][TN] = {};

  for (int k0 = 0; k0 < Kd; k0 += 64) {
    __syncthreads();
    #pragma unroll
    for (int i = 0; i < BM / 32; ++i) {
      int r0 = wid * (BM / 4) + i * 8;
      int r = r0 + lrow;
      int qg = lq ^ (r & 7);
      gld_lds16(A + (size_t)(m0 + r) * Kd + k0 + qg * 8, &lsA[r0 * 64]);
    }
    #pragma unroll
    for (int i = 0; i < BN / 32; ++i) {
      int r0 = wid * (BN / 4) + i * 8;
      int r = r0 + lrow;
      int qg = lq ^ (r & 7);
      gld_lds16(W + (size_t)(n0 + r) * Kd + k0 + qg * 8, &lsB[r0 * 64]);
    }
    __syncthreads();
    #pragma unroll
    for (int kk = 0; kk < 2; ++kk) {
      short8 aF[TM], bF[TN];
      int cc = (kk << 2) + quad;
      int cp = (cc ^ mx) << 3;
      #pragma unroll
      for (int t = 0; t < TM; ++t)
        aF[t] = *(const short8*)&lsA[(wm * (BM / 2) + t * 16 + mloc) * 64 + cp];
      #pragma unroll
      for (int t = 0; t < TN; ++t)
        bF[t] = *(const short8*)&lsB[(wn * (BN / 2) + t * 16 + mloc) * 64 + cp];
      #pragma unroll
      for (int tm = 0; tm < TM; ++tm)
        #pragma unroll
        for (int tn = 0; tn < TN; ++tn)
          acc[tm][tn] = __builtin_amdgcn_mfma_f32_16x16x32_bf16(
              aF[tm], bF[tn], acc[tm][tn], 0, 0, 0);
    }
  }

  #pragma unroll
  for (int tm = 0; tm < TM; ++tm) {
    #pragma unroll
    for (int reg = 0; reg < 4; ++reg) {
      int row = m0 + wm * (BM / 2) + tm * 16 + quad * 4 + reg;
      #pragma unroll
      for (int tn = 0; tn < TN; ++tn) {
        int col = n0 + wn * (BN / 2) + tn * 16 + mloc;
        float v = acc[tm][tn][reg];
        if (MODE == 0) {
          Cb[(size_t)row * Nd + col] = __float2bfloat16(v);
        } else {
          Cf[(size_t)row * Nd + col] = v + R[(size_t)row * Nd + col];
        }
      }
    }
  }
}

// ---------------- 3+4. fused conv+SiLU -> x_proj, K-SPLIT (2 blocks/tile) ----------
// Block = (tile, khalf). Each block: stages 19 rows x 512 e, convs its 512 channels
// (2 e/thread), x_proj partial over K=512 (bF[16] prefetch = 64 VGPR), atomicAdd
// fp32 partials into dbc[64] (cols 0-31 = dlt, 32-63 = B/C). Aggregate fixed cost
// (weight reads, staging bytes) unchanged vs 1-block/tile; serial chain halved,
// occupancy 2 blocks/CU (r12-confirmed lever).
__global__ __launch_bounds__(256, 2) void cpk_k(const bf16* __restrict__ xzb,
                                                const float* __restrict__ cw,
                                                const float* __restrict__ cb,
                                                const bf16* __restrict__ xpb,
                                                bf16* __restrict__ xsb,
                                                float* __restrict__ dbc) {
  __shared__ __align__(16) short lsXZ[19 * 512];  // staged xz x-half rows, this K-half
  __shared__ __align__(16) short lsX[16 * 512];   // xs tile, chunk-XOR swizzled
  int t = threadIdx.x, lane = t & 63, wv = t >> 6;
  int ml = lane & 15, quad = lane >> 4, mx = ml & 7;
  int tile = blockIdx.x >> 1, kb = blockIdx.x & 1;
  int m0 = tile * 16;
  int bs = m0 & ~(Ld - 1);  // batch start row
  int ek = kb * 512;        // this block's e-range start

  // phase A: stage xz x-half rows [m0-3, m0+16) x [ek, ek+512)
  #pragma unroll
  for (int p = 0; p < 5; ++p) {
    int idx8 = t + p * 256;
    if (idx8 < 19 * 64) {
      int r = idx8 >> 6;
      int e = (idx8 & 63) * 8;
      int g = m0 - 3 + r;
      short8 v = {0, 0, 0, 0, 0, 0, 0, 0};
      if (g >= bs) v = *(const short8*)(xzb + (size_t)g * (2 * Ed) + ek + e);
      *(short8*)&lsXZ[r * 512 + e] = v;
    }
  }

  // weight prefetch (half-K): wave wv -> output cols wv*16..+15
  short8 bF[16];
  #pragma unroll
  for (int ks = 0; ks < 16; ++ks)
    bF[ks] = *(const short8*)(xpb + (size_t)(wv * 16 + ml) * Ed + ek + ks * 32 + quad * 8);
  __syncthreads();

  // phase B: conv(K=4)+bias+SiLU on 2 consecutive e; write global + swizzled LDS
  {
    int el = t * 2;           // local e in [0,512)
    int eg = ek + el;         // global e
    int c8 = el >> 3, off = el & 7;
    float4 cw0 = *(const float4*)(cw + (size_t)eg * 4);
    float4 cw1 = *(const float4*)(cw + (size_t)(eg + 1) * 4);
    float cb0 = cb[eg], cb1 = cb[eg + 1];
    unsigned int r0u = *(const unsigned int*)&lsXZ[0 * 512 + el];
    unsigned int r1u = *(const unsigned int*)&lsXZ[1 * 512 + el];
    unsigned int r2u = *(const unsigned int*)&lsXZ[2 * 512 + el];
    float a0 = s2f((short)(r0u & 0xffff)), b0 = s2f((short)(r0u >> 16));
    float a1 = s2f((short)(r1u & 0xffff)), b1 = s2f((short)(r1u >> 16));
    float a2 = s2f((short)(r2u & 0xffff)), b2 = s2f((short)(r2u >> 16));
    #pragma unroll
    for (int r = 0; r < 16; ++r) {
      unsigned int r3u = *(const unsigned int*)&lsXZ[(r + 3) * 512 + el];
      float a3 = s2f((short)(r3u & 0xffff)), b3 = s2f((short)(r3u >> 16));
      float va = cb0 + cw0.x * a0 + cw0.y * a1 + cw0.z * a2 + cw0.w * a3;
      float vb = cb1 + cw1.x * b0 + cw1.y * b1 + cw1.z * b2 + cw1.w * b3;
      va = va / (1.f + __expf(-va));
      vb = vb / (1.f + __expf(-vb));
      unsigned int pk = (unsigned int)f2s(va) | ((unsigned int)f2s(vb) << 16);
      *(unsigned int*)(xsb + (size_t)(m0 + r) * Ed + eg) = pk;
      *(unsigned int*)&lsX[r * 512 + (((c8 ^ (r & 7)) << 3)) + off] = pk;
      a0 = a1; a1 = a2; a2 = a3;
      b0 = b1; b1 = b2; b2 = b3;
    }
  }
  __syncthreads();

  // phase C: x_proj partial MFMA (K=512), atomicAdd into dbc
  f32x4 acc = {0.f, 0.f, 0.f, 0.f};
  #pragma unroll
  for (int ks = 0; ks < 16; ++ks) {
    int cc = ks * 4 + quad;
    short8 aF = *(const short8*)&lsX[ml * 512 + ((cc ^ mx) << 3)];
    acc = __builtin_amdgcn_mfma_f32_16x16x32_bf16(aF, bF[ks], acc, 0, 0, 0);
  }
  #pragma unroll
  for (int reg = 0; reg < 4; ++reg)
    atomicAdd(&dbc[(size_t)(m0 + quad * 4 + reg) * 64 + wv * 16 + ml], acc[reg]);
}

// ---------------- 5-6. dt_proj + softplus -> bf16 delta (grid 1024) ----------------
// dlt now read as fp32 from dbc cols 0..31 (atomic-accumulated), cast to fragments.
__global__ __launch_bounds__(256) void pk2_k(const float* __restrict__ dbc,
                                             const bf16* __restrict__ dtb,
                                             const float* __restrict__ dt_b,
                                             bf16* __restrict__ delta) {
  int t = threadIdx.x, lane = t & 63, wv = t >> 6;
  int ml = lane & 15, quad = lane >> 4;
  int rt = blockIdx.x & 255, cq = blockIdx.x >> 8;
  int m0 = rt * 16;
  int cb0 = cq * 256 + wv * 64;    // this wave: 4 col-groups of 16

  float4 a0 = *(const float4*)(dbc + (size_t)(m0 + ml) * 64 + quad * 8);
  float4 a1 = *(const float4*)(dbc + (size_t)(m0 + ml) * 64 + quad * 8 + 4);
  short8 aF;
  aF[0] = (short)f2s(a0.x); aF[1] = (short)f2s(a0.y);
  aF[2] = (short)f2s(a0.z); aF[3] = (short)f2s(a0.w);
  aF[4] = (short)f2s(a1.x); aF[5] = (short)f2s(a1.y);
  aF[6] = (short)f2s(a1.z); aF[7] = (short)f2s(a1.w);
  short8 bF[4];
  float bias[4];
  #pragma unroll
  for (int g = 0; g < 4; ++g) {
    int e = cb0 + g * 16 + ml;
    bF[g] = *(const short8*)(dtb + (size_t)e * Rr + quad * 8);
    bias[g] = dt_b[e];
  }
  #pragma unroll
  for (int g = 0; g < 4; ++g) {
    f32x4 dacc = {0.f, 0.f, 0.f, 0.f};
    dacc = __builtin_amdgcn_mfma_f32_16x16x32_bf16(aF, bF[g], dacc, 0, 0, 0);
    int e = cb0 + g * 16 + ml;
    #pragma unroll
    for (int reg = 0; reg < 4; ++reg) {
      float v = dacc[reg] + bias[g];
      v = (v > 20.f) ? v : log1pf(__expf(v));
      delta[(size_t)(m0 + quad * 4 + reg) * Ed + e] = __float2bfloat16(v);
    }
  }
}

// ---------------- 7a. chunk-local scan: one thread per (b,e,chunk) ----------------
__global__ __launch_bounds__(256) void scan1_k(const bf16* __restrict__ delta,
                                               const bf16* __restrict__ xs,
                                               const float* __restrict__ dbc,
                                               const float* __restrict__ Aw,
                                               float* __restrict__ Sbuf,
                                               float* __restrict__ Hbuf) {
  int bc = blockIdx.x & 127;         // b*NC + c
  int eblk = blockIdx.x >> 7;
  int e = eblk * 256 + threadIdx.x;
  int b = bc >> 6, c = bc & 63;
  float A0 = Aw[e * Nn];
  float h[16];
  #pragma unroll
  for (int n = 0; n < 16; ++n) h[n] = 0.f;
  float s = 0.f;
  size_t m0 = (size_t)b * Ld + (size_t)c * CS;
  const bf16* dp = delta + m0 * Ed + e;
  const bf16* xp = xs + m0 * Ed + e;
  const float4* bp = (const float4*)(dbc + m0 * 64 + 32);
  for (int l = 0; l < CS; l += 2) {
    float dv0 = b2f(dp[0]), dv1 = b2f(dp[Ed]);
    float xv0 = b2f(xp[0]), xv1 = b2f(xp[Ed]);
    float4 Bq0[4], Bq1[4];
    #pragma unroll
    for (int q = 0; q < 4; ++q) { Bq0[q] = bp[q]; Bq1[q] = bp[16 + q]; }
    const float* B0 = (const float*)Bq0;
    const float* B1 = (const float*)Bq1;
    {
      float r = __expf(dv0 * A0), dvx = dv0 * xv0, p = r;
      #pragma unroll
      for (int n = 0; n < 16; ++n) { h[n] = fmaf(p, h[n], B0[n] * dvx); p *= r; }
    }
    {
      float r = __expf(dv1 * A0), dvx = dv1 * xv1, p = r;
      #pragma unroll
      for (int n = 0; n < 16; ++n) { h[n] = fmaf(p, h[n], B1[n] * dvx); p *= r; }
    }
    s += dv0 + dv1;
    dp += 2 * Ed; xp += 2 * Ed; bp += 32;
  }
  size_t ch = (size_t)bc * Ed + e;
  Sbuf[ch] = s;
  float4* Hp = (float4*)(Hbuf + ch * 16);
  #pragma unroll
  for (int q = 0; q < 4; ++q) Hp[q] = ((float4*)h)[q];
}

// ---------------- 7b. chunk-prefix fix-up ----------------
__global__ __launch_bounds__(256) void scan2_k(const float* __restrict__ Sbuf,
                                               const float* __restrict__ Aw,
                                               float* __restrict__ Hbuf) {
  int idx = blockIdx.x * 256 + threadIdx.x;
  int n = idx & 15;
  int be = idx >> 4;
  int e = be & (Ed - 1);
  int b = be >> 10;
  float An = Aw[e * Nn + n];
  float h = 0.f;
  for (int c0 = 0; c0 < NC; c0 += 8) {
    float sv[8], hv[8];
    size_t ix[8];
    #pragma unroll
    for (int j = 0; j < 8; ++j) {
      size_t ch = (size_t)(b * NC + c0 + j) * Ed + e;
      ix[j] = ch * 16 + n;
      sv[j] = Sbuf[ch];
      hv[j] = Hbuf[ix[j]];
    }
    #pragma unroll
    for (int j = 0; j < 8; ++j) {
      Hbuf[ix[j]] = h;
      h = __expf(sv[j] * An) * h + hv[j];
    }
  }
}

// ---------------- 7c. re-scan from h_enter + y = C.h + D*xs, SiLU(z) gate ------------
__global__ __launch_bounds__(256) void scan3_k(const bf16* __restrict__ delta,
                                               const bf16* __restrict__ xs,
                                               const float* __restrict__ dbc,
                                               const bf16* __restrict__ xz,
                                               const float* __restrict__ Aw,
                                               const float* __restrict__ Dw,
                                               const float* __restrict__ Hbuf,
                                               bf16* __restrict__ yg) {
  int bc = blockIdx.x & 127;
  int eblk = blockIdx.x >> 7;
  int e = eblk * 256 + threadIdx.x;
  int b = bc >> 6, c = bc & 63;
  float A0 = Aw[e * Nn];
  float De = Dw[e];
  size_t ch = (size_t)bc * Ed + e;
  float h[16];
  #pragma unroll
  for (int q = 0; q < 4; ++q)
    ((float4*)h)[q] = ((const float4*)(Hbuf + ch * 16))[q];
  size_t m0 = (size_t)b * Ld + (size_t)c * CS;
  const bf16* dp = delta + m0 * Ed + e;
  const bf16* xp = xs + m0 * Ed + e;
  const float4* bp = (const float4*)(dbc + m0 * 64 + 32);  // [B(16)|C(16)]
  const bf16* zp = xz + m0 * (2 * Ed) + Ed + e;
  bf16* yp = yg + m0 * Ed + e;
  for (int l = 0; l < CS; l += 2) {
    float dv0 = b2f(dp[0]), dv1 = b2f(dp[Ed]);
    float xv0 = b2f(xp[0]), xv1 = b2f(xp[Ed]);
    float zv0 = b2f(zp[0]), zv1 = b2f(zp[2 * Ed]);
    float4 Q0[8], Q1[8];
    #pragma unroll
    for (int q = 0; q < 8; ++q) { Q0[q] = bp[q]; Q1[q] = bp[16 + q]; }
    const float* B0 = (const float*)Q0;        // B = [0..16), C = [16..32)
    const float* B1 = (const float*)Q1;
    {
      float r = __expf(dv0 * A0), dvx = dv0 * xv0, p = r;
      float y0 = 0.f, y1 = 0.f, y2 = 0.f, y3 = 0.f;
      #pragma unroll
      for (int n = 0; n < 16; ++n) {
        h[n] = fmaf(p, h[n], B0[n] * dvx);
        if ((n & 3) == 0) y0 = fmaf(h[n], B0[16 + n], y0);
        else if ((n & 3) == 1) y1 = fmaf(h[n], B0[16 + n], y1);
        else if ((n & 3) == 2) y2 = fmaf(h[n], B0[16 + n], y2);
        else y3 = fmaf(h[n], B0[16 + n], y3);
        p *= r;
      }
      float y = (y0 + y1) + (y2 + y3);
      float ytot = fmaf(De, xv0, y);
      float g = zv0 / (1.f + __expf(-zv0));
      yp[0] = __float2bfloat16(ytot * g);
    }
    {
      float r = __expf(dv1 * A0), dvx = dv1 * xv1, p = r;
      float y0 = 0.f, y1 = 0.f, y2 = 0.f, y3 = 0.f;
      #pragma unroll
      for (int n = 0; n < 16; ++n) {
        h[n] = fmaf(p, h[n], B1[n] * dvx);
        if ((n & 3) == 0) y0 = fmaf(h[n], B1[16 + n], y0);
        else if ((n & 3) == 1) y1 = fmaf(h[n], B1[16 + n], y1);
        else if ((n & 3) == 2) y2 = fmaf(h[n], B1[16 + n], y2);
        else y3 = fmaf(h[n], B1[16 + n], y3);
        p *= r;
      }
      float y = (y0 + y1) + (y2 + y3);
      float ytot = fmaf(De, xv1, y);
      float g = zv1 / (1.f + __expf(-zv1));
      yp[Ed] = __float2bfloat16(ytot * g);
    }
    dp += 2 * Ed; xp += 2 * Ed; bp += 32; zp += 4 * Ed; yp += 2 * Ed;
  }
}

extern "C" void kernel_launch(void* const* d_in, const int* in_sizes, int n_in,
                              void* d_out, int out_size, void* d_ws, size_t ws_size,
                              hipStream_t stream) {
  const float* x        = (const float*)d_in[0];
  const float* norm_w   = (const float*)d_in[1];
  const float* in_proj  = (const float*)d_in[2];
  const float* conv_w   = (const float*)d_in[3];
  const float* conv_b   = (const float*)d_in[4];
  const float* x_proj   = (const float*)d_in[5];
  const float* dt_proj  = (const float*)d_in[6];
  const float* dt_b     = (const float*)d_in[7];
  const float* Aw       = (const float*)d_in[8];
  const float* Dw       = (const float*)d_in[9];
  const float* out_proj = (const float*)d_in[10];
  float* out = (float*)d_out;

  // workspace layout (~57 MB, < 76.5 MB proven)
  char* w = (char*)d_ws;
  bf16*  xzb   = (bf16*)w;   w += (size_t)Md * 2 * Ed * 2;        // 16 MB
  bf16*  xsb   = (bf16*)w;   w += (size_t)Md * Ed * 2;            //  8 MB
  float* dbc   = (float*)w;  w += (size_t)Md * 64 * 4;            //  1 MB
  bf16*  delta = (bf16*)w;   w += (size_t)Md * Ed * 2;            //  8 MB
  bf16*  ygb   = (bf16*)w;   w += (size_t)Md * Ed * 2;            //  8 MB
  bf16*  xnb   = (bf16*)w;   w += (size_t)Md * DM * 2;            //  4 MB
  bf16*  ipb   = (bf16*)w;   w += (size_t)2 * Ed * DM * 2;        //  2 MB
  bf16*  opb   = (bf16*)w;   w += (size_t)DM * Ed * 2;            //  1 MB
  bf16*  xpb   = (bf16*)w;   w += (size_t)64 * Ed * 2;            // 128 KB
  bf16*  dtb   = (bf16*)w;   w += (size_t)Ed * Rr * 2;            //  64 KB
  float* Sbuf  = (float*)w;  w += (size_t)Bd * Ed * NC * 4;       // 512 KB
  float* Hbuf  = (float*)w;                                       //  8 MB

  // 0+1. merged weight casts + dbc zero + RMSNorm
  castnorm_k<<<1888 + Md, 256, 0, stream>>>(in_proj, out_proj, x_proj, dt_proj,
                                            ipb, opb, xpb, dtb, dbc, x, norm_w, xnb);
  // 2. xz = xn @ in_proj^T  [4096 x 2048], K=512 (MFMA 128x128 -- r12-proven)
  gemm_mfma<0, 128, 128><<<dim3(2 * Ed / 128, Md / 128), 256, 0, stream>>>(
      xnb, ipb, xzb, nullptr, nullptr, DM, 2 * Ed);
  // 3+4. fused conv+silu -> x_proj, K-split (512 blocks = 2/CU)
  cpk_k<<<(Md / 16) * 2, 256, 0, stream>>>(xzb, conv_w, conv_b, xpb, xsb, dbc);
  // 5-6. dt_proj + softplus -> bf16 delta (grid 1024)
  pk2_k<<<(Md / 16) * 4, 256, 0, stream>>>(dbc, dtb, dt_b, delta);
  // 7. chunked scan (thread-per-channel)
  scan1_k<<<(Bd * Ed * NC) / 256, 256, 0, stream>>>(delta, xsb, dbc, Aw, Sbuf, Hbuf);
  scan2_k<<<(Bd * Ed * Nn) / 256, 256, 0, stream>>>(Sbuf, Aw, Hbuf);
  scan3_k<<<(Bd * Ed * NC) / 256, 256, 0, stream>>>(delta, xsb, dbc, xzb, Aw, Dw, Hbuf, ygb);
  // 8. out = yg @ out_proj^T + x  [4096 x 512], K=1024 (MFMA 64x64, 512 blocks ~2/CU)
  gemm_mfma<1, 64, 64><<<dim3(DM / 64, Md / 64), 256, 0, stream>>>(
      ygb, opb, nullptr, out, x, Ed, DM);
}